// Round 1
// baseline (1228.760 us; speedup 1.0000x reference)
//
#include <hip/hip_runtime.h>

// Problem constants (RecurrentModel: 2-layer GRU stack)
#define T_    256
#define B_    256
#define IN_   64
#define HID_  512
#define LS_   256
#define G3_   768   // 3*LS
// Decomposition: grid = NTB_ time-blocks x NBG_ batch-groups = 256 wgs (1/CU)
#define TB_   8     // timesteps per block (plus ~5 lookback warmup)
#define NTB_  32
#define MB_   32    // batch elems per wg (2 MFMA M-tiles)
#define NBG_  8
#define LSP_  264   // LDS row pitch (256 + 8 bf16 -> 16B pad, 2-way-bank = free)

typedef short bf16x8v __attribute__((ext_vector_type(8)));
typedef float f32x4  __attribute__((ext_vector_type(4)));

#define MFMA_B16(A, B, C) __builtin_amdgcn_mfma_f32_16x16x32_bf16(A, B, C, 0, 0, 0)

__device__ __forceinline__ unsigned short f2bf(float f) {
  union { float f; unsigned u; } v; v.f = f;
  unsigned r = v.u + 0x7fffu + ((v.u >> 16) & 1u);   // RNE
  return (unsigned short)(r >> 16);
}
__device__ __forceinline__ float bf2f(unsigned short b) {
  union { unsigned u; float f; } v; v.u = ((unsigned)b) << 16;
  return v.f;
}
__device__ __forceinline__ float sigm(float x) { return 1.0f / (1.0f + __expf(-x)); }
__device__ __forceinline__ float tanh_f(float x) {
  x = fminf(fmaxf(x, -15.0f), 15.0f);
  float e = __expf(-2.0f * x);
  return (1.0f - e) / (1.0f + e);
}

// ---------------- prep kernel 1: bf16 weight conversion + reset-layout sniff ----
// dst is contiguous [whh0_bf | wih1_bf | whh1_bf], each 768*256 bf16.
__global__ void prep_conv(const float* __restrict__ whh0, const float* __restrict__ wih1,
                          const float* __restrict__ whh1, const unsigned char* __restrict__ rst,
                          unsigned short* __restrict__ dst, int* __restrict__ flagp) {
  const int idx = blockIdx.x * blockDim.x + threadIdx.x;
  const int N1 = G3_ * LS_;  // 196608
  if (idx < 3 * N1) {
    float v;
    if (idx < N1)            v = whh0[idx];
    else if (idx < 2 * N1)   v = wih1[idx - N1];
    else                     v = whh1[idx - 2 * N1];
    dst[idx] = f2bf(v);
  }
  // block 0: detect reset layout. int32 bools -> bytes at off%4!=0 are all zero.
  if (blockIdx.x == 0) {
    __shared__ int f;
    if (threadIdx.x == 0) f = 0;
    __syncthreads();
    int any = 0;
    for (int i = 0; i < 8; ++i) {
      int off = threadIdx.x * 8 + i;             // scans first 4096 bytes
      if ((off & 3) && rst[off]) any = 1;
    }
    if (any) atomicOr(&f, 1);
    __syncthreads();
    if (threadIdx.x == 0) *flagp = f;            // 1 => byte-packed (int8) reset
  }
}

// ---------------- prep kernel 2: fused embed weight W_c = w_ih0 @ W_lin --------
// W_c [768][64] bf16; b_c [768] f32 = w_ih0 @ b_lin + b_ih0.
__global__ void prep_wc(const float* __restrict__ W_lin, const float* __restrict__ b_lin,
                        const float* __restrict__ w_ih0, const float* __restrict__ b_ih0,
                        unsigned short* __restrict__ wc, float* __restrict__ bc) {
  const int n = blockIdx.x;   // 0..767
  const int i = threadIdx.x;  // 0..63
  const float* wrow = w_ih0 + (size_t)n * HID_;
  float acc = 0.f;
  for (int h = 0; h < HID_; ++h) acc += wrow[h] * W_lin[h * IN_ + i];
  wc[n * IN_ + i] = f2bf(acc);
  float pb = 0.f;
  for (int h = i; h < HID_; h += 64) pb += wrow[h] * b_lin[h];
  __shared__ float red[64];
  red[i] = pb;
  __syncthreads();
  if (i == 0) {
    float s = 0.f;
    for (int k = 0; k < 64; ++k) s += red[k];
    bc[n] = s + b_ih0[n];
  }
}

// ---------------- main recurrent kernel ----------------------------------------
__global__ __launch_bounds__(512, 2) void gru_main(
    const float* __restrict__ obs, const unsigned char* __restrict__ rst,
    const float* __restrict__ h_init,
    const unsigned short* __restrict__ wc,   // [768][64] bf16
    const unsigned short* __restrict__ whh0, // [768][256] bf16
    const unsigned short* __restrict__ wih1, const unsigned short* __restrict__ whh1,
    const float* __restrict__ bc, const float* __restrict__ bhh0,
    const float* __restrict__ bih1, const float* __restrict__ bhh1,
    const int* __restrict__ flagp, float* __restrict__ out) {

  __shared__ __align__(16) unsigned short h0b[MB_][LSP_];  // bf16 state (matmul feed)
  __shared__ __align__(16) unsigned short h1b[MB_][LSP_];
  __shared__ float sbias[4 * G3_];   // bc | bhh0 | bih1 | bhh1
  __shared__ int s_sm[MB_];
  __shared__ int s_start_sh;

  const int tid  = threadIdx.x;
  const int lane = tid & 63;
  const int wave = tid >> 6;          // 0..7, owns ls-cols [wave*32, wave*32+32)
  const int l15  = lane & 15;
  const int quad = lane >> 4;
  const int c0   = wave * 32;

  const int t0 = blockIdx.x * TB_;
  const int b0 = blockIdx.y * MB_;
  const int flag = *flagp;
#define RVAL(i) (rst[flag ? (i) : ((i) << 2)] != 0)

  for (int i = tid; i < G3_; i += 512) {
    sbias[i]           = bc[i];
    sbias[G3_ + i]     = bhh0[i];
    sbias[2 * G3_ + i] = bih1[i];
    sbias[3 * G3_ + i] = bhh1[i];
  }
  // per-elem last reset <= t0 (state zeroed AT a reset step, so starting there with h=0
  // is exact; elems whose own reset is later get wiped by masking before t0)
  if (tid < MB_) {
    int s = 0;
    for (int tt = t0; tt >= 1; --tt) {
      if (RVAL(tt * B_ + b0 + tid)) { s = tt; break; }
    }
    s_sm[tid] = s;
  }
  __syncthreads();
  if (tid == 0) {
    int s = s_sm[0];
    for (int k = 1; k < MB_; ++k) s = s < s_sm[k] ? s : s_sm[k];
    s_start_sh = s;
  }
  __syncthreads();
  const int s_start = s_start_sh;

  // init LDS bf16 state (h_init when starting at t=0, else zeros)
  for (int i = tid; i < MB_ * LS_; i += 512) {
    int m = i >> 8, k = i & (LS_ - 1);
    float v0 = 0.f, v1 = 0.f;
    if (s_start == 0) {
      v0 = h_init[(size_t)(b0 + m) * HID_ + k];
      v1 = h_init[(size_t)(b0 + m) * HID_ + LS_ + k];
    }
    h0b[m][k] = f2bf(v0);
    h1b[m][k] = f2bf(v1);
  }
  // fp32 register-resident state copy: lane owns rows m=mt*16+quad*4+r, col c0+lt*16+l15.
  // This keeps the z*h carry path full precision (bf16 only feeds the matmuls).
  float h0v[2][2][4], h1v[2][2][4];
#pragma unroll
  for (int lt = 0; lt < 2; ++lt)
#pragma unroll
    for (int mt = 0; mt < 2; ++mt)
#pragma unroll
      for (int r = 0; r < 4; ++r) {
        const int m = mt * 16 + quad * 4 + r;
        const int c = c0 + lt * 16 + l15;
        float v0 = 0.f, v1 = 0.f;
        if (s_start == 0) {
          v0 = h_init[(size_t)(b0 + m) * HID_ + c];
          v1 = h_init[(size_t)(b0 + m) * HID_ + LS_ + c];
        }
        h0v[lt][mt][r] = v0;
        h1v[lt][mt][r] = v1;
      }
  __syncthreads();

  const bf16x8v z8 = {0, 0, 0, 0, 0, 0, 0, 0};

  for (int t = s_start; t < t0 + TB_; ++t) {
    const bool wr = (t >= t0);
    const int ridx = t * B_ + b0;
    // masks: A-frag rows (m = l15 / 16+l15) and epilogue rows (m = mt*16+quad*4+r)
    const bool rs_a0 = RVAL(ridx + l15);
    const bool rs_a1 = RVAL(ridx + 16 + l15);
    bool rs_e[2][4];
#pragma unroll
    for (int mt = 0; mt < 2; ++mt)
#pragma unroll
      for (int r = 0; r < 4; ++r) rs_e[mt][r] = RVAL(ridx + mt * 16 + quad * 4 + r);

    // ================= layer 0 =================
    f32x4 a_r[2][2], a_z[2][2], a_i[2][2], a_h[2][2];  // [ls_tile][m_tile]
#pragma unroll
    for (int lt = 0; lt < 2; ++lt)
#pragma unroll
      for (int mt = 0; mt < 2; ++mt) {
        a_r[lt][mt] = (f32x4){0.f, 0.f, 0.f, 0.f};
        a_z[lt][mt] = (f32x4){0.f, 0.f, 0.f, 0.f};
        a_i[lt][mt] = (f32x4){0.f, 0.f, 0.f, 0.f};
        a_h[lt][mt] = (f32x4){0.f, 0.f, 0.f, 0.f};
      }

    // ig0 = obs @ W_c^T  (NOT masked), folded into r/z accs; n-gate input side in a_i
#pragma unroll
    for (int kc = 0; kc < 2; ++kc) {
      const float* p0 = obs + ((size_t)t * B_ + b0 + l15) * IN_ + kc * 32 + quad * 8;
      const float* p1 = p0 + (size_t)16 * IN_;
      float4 x0 = *(const float4*)p0;
      float4 x1 = *(const float4*)(p0 + 4);
      float4 y0 = *(const float4*)p1;
      float4 y1 = *(const float4*)(p1 + 4);
      bf16x8v a0, a1;
      a0[0] = (short)f2bf(x0.x); a0[1] = (short)f2bf(x0.y);
      a0[2] = (short)f2bf(x0.z); a0[3] = (short)f2bf(x0.w);
      a0[4] = (short)f2bf(x1.x); a0[5] = (short)f2bf(x1.y);
      a0[6] = (short)f2bf(x1.z); a0[7] = (short)f2bf(x1.w);
      a1[0] = (short)f2bf(y0.x); a1[1] = (short)f2bf(y0.y);
      a1[2] = (short)f2bf(y0.z); a1[3] = (short)f2bf(y0.w);
      a1[4] = (short)f2bf(y1.x); a1[5] = (short)f2bf(y1.y);
      a1[6] = (short)f2bf(y1.z); a1[7] = (short)f2bf(y1.w);
#pragma unroll
      for (int lt = 0; lt < 2; ++lt) {
        const int row = c0 + lt * 16 + l15;
        const unsigned short* pb = wc + (size_t)row * IN_ + kc * 32 + quad * 8;
        bf16x8v br = *(const bf16x8v*)pb;
        bf16x8v bz = *(const bf16x8v*)(pb + 256 * IN_);
        bf16x8v bn = *(const bf16x8v*)(pb + 512 * IN_);
        a_r[lt][0] = MFMA_B16(a0, br, a_r[lt][0]); a_r[lt][1] = MFMA_B16(a1, br, a_r[lt][1]);
        a_z[lt][0] = MFMA_B16(a0, bz, a_z[lt][0]); a_z[lt][1] = MFMA_B16(a1, bz, a_z[lt][1]);
        a_i[lt][0] = MFMA_B16(a0, bn, a_i[lt][0]); a_i[lt][1] = MFMA_B16(a1, bn, a_i[lt][1]);
      }
    }
    // h-side gates: (mask*h0) @ w_hh0^T ; n-gate h-side into a_h
#pragma unroll
    for (int kc = 0; kc < 8; ++kc) {
      bf16x8v a0 = *(const bf16x8v*)&h0b[l15][kc * 32 + quad * 8];
      bf16x8v a1 = *(const bf16x8v*)&h0b[16 + l15][kc * 32 + quad * 8];
      if (rs_a0) a0 = z8;
      if (rs_a1) a1 = z8;
#pragma unroll
      for (int lt = 0; lt < 2; ++lt) {
        const int row = c0 + lt * 16 + l15;
        const unsigned short* pb = whh0 + (size_t)row * LS_ + kc * 32 + quad * 8;
        bf16x8v br = *(const bf16x8v*)pb;
        bf16x8v bz = *(const bf16x8v*)(pb + 256 * LS_);
        bf16x8v bn = *(const bf16x8v*)(pb + 512 * LS_);
        a_r[lt][0] = MFMA_B16(a0, br, a_r[lt][0]); a_r[lt][1] = MFMA_B16(a1, br, a_r[lt][1]);
        a_z[lt][0] = MFMA_B16(a0, bz, a_z[lt][0]); a_z[lt][1] = MFMA_B16(a1, bz, a_z[lt][1]);
        a_h[lt][0] = MFMA_B16(a0, bn, a_h[lt][0]); a_h[lt][1] = MFMA_B16(a1, bn, a_h[lt][1]);
      }
    }
    __syncthreads();  // S1: all h0 A-frag reads done before in-place h0n writes

    // epilogue 0: GRU cell, fp32 carry, write h0n (LDS bf16 + global out)
#pragma unroll
    for (int lt = 0; lt < 2; ++lt) {
      const int c = c0 + lt * 16 + l15;
      const float br_ = sbias[c] + sbias[G3_ + c];
      const float bz_ = sbias[c + 256] + sbias[G3_ + c + 256];
      const float bi_ = sbias[c + 512];
      const float bh_ = sbias[G3_ + c + 512];
#pragma unroll
      for (int mt = 0; mt < 2; ++mt)
#pragma unroll
        for (int r = 0; r < 4; ++r) {
          const int m = mt * 16 + quad * 4 + r;
          float rr = sigm(a_r[lt][mt][r] + br_);
          float zz = sigm(a_z[lt][mt][r] + bz_);
          float nn = tanh_f(a_i[lt][mt][r] + bi_ + rr * (a_h[lt][mt][r] + bh_));
          float hp = rs_e[mt][r] ? 0.f : h0v[lt][mt][r];
          float hv = (1.f - zz) * nn + zz * hp;
          h0v[lt][mt][r] = hv;
          h0b[m][c] = f2bf(hv);
          if (wr) out[((size_t)t * B_ + b0 + m) * HID_ + c] = hv;
        }
    }
    __syncthreads();  // S2: h0n complete before layer-1 reads it

    // ================= layer 1 =================
#pragma unroll
    for (int lt = 0; lt < 2; ++lt)
#pragma unroll
      for (int mt = 0; mt < 2; ++mt) {
        a_r[lt][mt] = (f32x4){0.f, 0.f, 0.f, 0.f};
        a_z[lt][mt] = (f32x4){0.f, 0.f, 0.f, 0.f};
        a_i[lt][mt] = (f32x4){0.f, 0.f, 0.f, 0.f};
        a_h[lt][mt] = (f32x4){0.f, 0.f, 0.f, 0.f};
      }
#pragma unroll
    for (int kc = 0; kc < 8; ++kc) {
      bf16x8v an0 = *(const bf16x8v*)&h0b[l15][kc * 32 + quad * 8];       // h0n (unmasked)
      bf16x8v an1 = *(const bf16x8v*)&h0b[16 + l15][kc * 32 + quad * 8];
      bf16x8v ah0 = *(const bf16x8v*)&h1b[l15][kc * 32 + quad * 8];       // mask*h1
      bf16x8v ah1 = *(const bf16x8v*)&h1b[16 + l15][kc * 32 + quad * 8];
      if (rs_a0) ah0 = z8;
      if (rs_a1) ah1 = z8;
#pragma unroll
      for (int lt = 0; lt < 2; ++lt) {
        const int row = c0 + lt * 16 + l15;
        const unsigned short* pi = wih1 + (size_t)row * LS_ + kc * 32 + quad * 8;
        const unsigned short* ph = whh1 + (size_t)row * LS_ + kc * 32 + quad * 8;
        bf16x8v bir = *(const bf16x8v*)pi;
        bf16x8v biz = *(const bf16x8v*)(pi + 256 * LS_);
        bf16x8v bin = *(const bf16x8v*)(pi + 512 * LS_);
        bf16x8v bhr = *(const bf16x8v*)ph;
        bf16x8v bhz = *(const bf16x8v*)(ph + 256 * LS_);
        bf16x8v bhn = *(const bf16x8v*)(ph + 512 * LS_);
        a_r[lt][0] = MFMA_B16(an0, bir, a_r[lt][0]);
        a_r[lt][0] = MFMA_B16(ah0, bhr, a_r[lt][0]);
        a_r[lt][1] = MFMA_B16(an1, bir, a_r[lt][1]);
        a_r[lt][1] = MFMA_B16(ah1, bhr, a_r[lt][1]);
        a_z[lt][0] = MFMA_B16(an0, biz, a_z[lt][0]);
        a_z[lt][0] = MFMA_B16(ah0, bhz, a_z[lt][0]);
        a_z[lt][1] = MFMA_B16(an1, biz, a_z[lt][1]);
        a_z[lt][1] = MFMA_B16(ah1, bhz, a_z[lt][1]);
        a_i[lt][0] = MFMA_B16(an0, bin, a_i[lt][0]);
        a_i[lt][1] = MFMA_B16(an1, bin, a_i[lt][1]);
        a_h[lt][0] = MFMA_B16(ah0, bhn, a_h[lt][0]);
        a_h[lt][1] = MFMA_B16(ah1, bhn, a_h[lt][1]);
      }
    }
    __syncthreads();  // S3: all h1 A-frag reads done before in-place h1n writes

#pragma unroll
    for (int lt = 0; lt < 2; ++lt) {
      const int c = c0 + lt * 16 + l15;
      const float br_ = sbias[2 * G3_ + c] + sbias[3 * G3_ + c];
      const float bz_ = sbias[2 * G3_ + c + 256] + sbias[3 * G3_ + c + 256];
      const float bi_ = sbias[2 * G3_ + c + 512];
      const float bh_ = sbias[3 * G3_ + c + 512];
#pragma unroll
      for (int mt = 0; mt < 2; ++mt)
#pragma unroll
        for (int r = 0; r < 4; ++r) {
          const int m = mt * 16 + quad * 4 + r;
          float rr = sigm(a_r[lt][mt][r] + br_);
          float zz = sigm(a_z[lt][mt][r] + bz_);
          float nn = tanh_f(a_i[lt][mt][r] + bi_ + rr * (a_h[lt][mt][r] + bh_));
          float hp = rs_e[mt][r] ? 0.f : h1v[lt][mt][r];
          float hv = (1.f - zz) * nn + zz * hp;
          h1v[lt][mt][r] = hv;
          h1b[m][c] = f2bf(hv);
          if (wr) out[((size_t)t * B_ + b0 + m) * HID_ + LS_ + c] = hv;
        }
    }
    // no sync needed here: next-iter S1 orders h1b writes before next layer-1 reads
  }
#undef RVAL
}

extern "C" void kernel_launch(void* const* d_in, const int* in_sizes, int n_in,
                              void* d_out, int out_size, void* d_ws, size_t ws_size,
                              hipStream_t stream) {
  const float* obs    = (const float*)d_in[0];
  const unsigned char* rst = (const unsigned char*)d_in[1];
  const float* h_init = (const float*)d_in[2];
  const float* W_lin  = (const float*)d_in[3];
  const float* b_lin  = (const float*)d_in[4];
  const float* w_ih0  = (const float*)d_in[5];
  const float* w_hh0  = (const float*)d_in[6];
  const float* b_ih0  = (const float*)d_in[7];
  const float* b_hh0  = (const float*)d_in[8];
  const float* w_ih1  = (const float*)d_in[9];
  const float* w_hh1  = (const float*)d_in[10];
  const float* b_ih1  = (const float*)d_in[11];
  const float* b_hh1  = (const float*)d_in[12];

  // workspace carve (all 16B-aligned offsets); re-written every launch (ws re-poisoned)
  char* w = (char*)d_ws;
  unsigned short* wc    = (unsigned short*)(w);             // 768*64  bf16 =  98304 B
  unsigned short* whh0b = (unsigned short*)(w + 98304);     // 768*256 bf16 = 393216 B
  unsigned short* wih1b = (unsigned short*)(w + 491520);
  unsigned short* whh1b = (unsigned short*)(w + 884736);
  float*          bcp   = (float*)(w + 1277952);            // 768 f32
  int*            flagp = (int*)(w + 1281024);

  prep_conv<<<1152, 512, 0, stream>>>(w_hh0, w_ih1, w_hh1, rst, whh0b, flagp);
  prep_wc<<<768, 64, 0, stream>>>(W_lin, b_lin, w_ih0, b_ih0, wc, bcp);
  gru_main<<<dim3(NTB_, NBG_), 512, 0, stream>>>(obs, rst, h_init, wc, whh0b, wih1b, whh1b,
                                                 bcp, b_hh0, b_ih1, b_hh1, flagp,
                                                 (float*)d_out);
}

// Round 3
// 1202.322 us; speedup vs baseline: 1.0220x; 1.0220x over previous
//
#include <hip/hip_runtime.h>

// Problem constants (RecurrentModel: 2-layer GRU stack)
#define T_    256
#define B_    256
#define IN_   64
#define HID_  512
#define LS_   256
#define G3_   768   // 3*LS
// Decomposition: grid = NTB_ time-blocks x NBG_ batch-groups = 256 wgs (1/CU)
#define TB_   8     // timesteps per block (plus ~2-6 lookback warmup)
#define NTB_  32
#define MB_   32    // batch elems per wg (2 MFMA M-tiles)
#define NBG_  8
#define LSP_  264   // LDS row pitch bf16 (256 + 8 -> 16B pad, 2-way-bank = free)
#define OSP_  260   // LDS row pitch f32 out-stage (256 + 4 -> 16B pad)

typedef short bf16x8v __attribute__((ext_vector_type(8)));
typedef float f32x4  __attribute__((ext_vector_type(4)));   // used for NT ld/st too

#define MFMA_B16(A, B, C) __builtin_amdgcn_mfma_f32_16x16x32_bf16(A, B, C, 0, 0, 0)

__device__ __forceinline__ unsigned short f2bf(float f) {
  union { float f; unsigned u; } v; v.f = f;
  unsigned r = v.u + 0x7fffu + ((v.u >> 16) & 1u);   // RNE
  return (unsigned short)(r >> 16);
}
__device__ __forceinline__ float sigm(float x) { return 1.0f / (1.0f + __expf(-x)); }
__device__ __forceinline__ float tanh_f(float x) {
  x = fminf(fmaxf(x, -15.0f), 15.0f);
  float e = __expf(-2.0f * x);
  return (1.0f - e) / (1.0f + e);
}

// ---------------- prep kernel 1: bf16 weight conversion + reset-layout sniff ----
__global__ void prep_conv(const float* __restrict__ whh0, const float* __restrict__ wih1,
                          const float* __restrict__ whh1, const unsigned char* __restrict__ rst,
                          unsigned short* __restrict__ dst, int* __restrict__ flagp) {
  const int idx = blockIdx.x * blockDim.x + threadIdx.x;
  const int N1 = G3_ * LS_;  // 196608
  if (idx < 3 * N1) {
    float v;
    if (idx < N1)            v = whh0[idx];
    else if (idx < 2 * N1)   v = wih1[idx - N1];
    else                     v = whh1[idx - 2 * N1];
    dst[idx] = f2bf(v);
  }
  // block 0: detect reset layout. int32 bools -> bytes at off%4!=0 are all zero.
  if (blockIdx.x == 0) {
    __shared__ int f;
    if (threadIdx.x == 0) f = 0;
    __syncthreads();
    int any = 0;
    for (int i = 0; i < 8; ++i) {
      int off = threadIdx.x * 8 + i;             // scans first 4096 bytes
      if ((off & 3) && rst[off]) any = 1;
    }
    if (any) atomicOr(&f, 1);
    __syncthreads();
    if (threadIdx.x == 0) *flagp = f;            // 1 => byte-packed (int8) reset
  }
}

// ---------------- prep kernel 2: fused embed weight W_c = w_ih0 @ W_lin --------
// W_c [768][64] bf16; b_c [768] f32 = w_ih0 @ b_lin + b_ih0.
__global__ void prep_wc(const float* __restrict__ W_lin, const float* __restrict__ b_lin,
                        const float* __restrict__ w_ih0, const float* __restrict__ b_ih0,
                        unsigned short* __restrict__ wc, float* __restrict__ bc) {
  const int n = blockIdx.x;   // 0..767
  const int i = threadIdx.x;  // 0..63
  const float* wrow = w_ih0 + (size_t)n * HID_;
  float acc = 0.f;
  for (int h = 0; h < HID_; ++h) acc += wrow[h] * W_lin[h * IN_ + i];
  wc[n * IN_ + i] = f2bf(acc);
  float pb = 0.f;
  for (int h = i; h < HID_; h += 64) pb += wrow[h] * b_lin[h];
  __shared__ float red[64];
  red[i] = pb;
  __syncthreads();
  if (i == 0) {
    float s = 0.f;
    for (int k = 0; k < 64; ++k) s += red[k];
    bc[n] = s + b_ih0[n];
  }
}

// ---------------- main recurrent kernel ----------------------------------------
__global__ __launch_bounds__(512, 2) void gru_main(
    const float* __restrict__ obs, const unsigned char* __restrict__ rst,
    const float* __restrict__ h_init,
    const unsigned short* __restrict__ wc,   // [768][64] bf16
    const unsigned short* __restrict__ whh0, // [768][256] bf16
    const unsigned short* __restrict__ wih1, const unsigned short* __restrict__ whh1,
    const float* __restrict__ bc, const float* __restrict__ bhh0,
    const float* __restrict__ bih1, const float* __restrict__ bhh1,
    const int* __restrict__ flagp, float* __restrict__ out) {

  __shared__ __align__(16) unsigned short h0b[MB_][LSP_];  // bf16 state (matmul feed)
  __shared__ __align__(16) unsigned short h1b[MB_][LSP_];
  __shared__ __align__(16) float ostage[MB_][OSP_];        // fp32 out staging (reused L0/L1)
  __shared__ float sbias[4 * G3_];   // bc | bhh0 | bih1 | bhh1
  __shared__ int s_sm[MB_];
  __shared__ int s_start_sh;

  const int tid  = threadIdx.x;
  const int lane = tid & 63;
  const int wave = tid >> 6;          // 0..7, owns ls-cols [wave*32, wave*32+32)
  const int l15  = lane & 15;
  const int quad = lane >> 4;
  const int c0   = wave * 32;

  const int t0 = blockIdx.x * TB_;
  const int b0 = blockIdx.y * MB_;
  const int flag = *flagp;
#define RVAL(i) (rst[flag ? (i) : ((i) << 2)] != 0)

  for (int i = tid; i < G3_; i += 512) {
    sbias[i]           = bc[i];
    sbias[G3_ + i]     = bhh0[i];
    sbias[2 * G3_ + i] = bih1[i];
    sbias[3 * G3_ + i] = bhh1[i];
  }
  // per-elem last reset <= t0 (state zeroed AT a reset step, so starting there with
  // h=0 is exact; elems whose own reset is later get wiped by masking before t0)
  if (tid < MB_) {
    int s = 0;
    for (int tt = t0; tt >= 1; --tt) {
      if (RVAL(tt * B_ + b0 + tid)) { s = tt; break; }
    }
    s_sm[tid] = s;
  }
  __syncthreads();
  if (tid == 0) {
    int s = s_sm[0];
    for (int k = 1; k < MB_; ++k) s = s < s_sm[k] ? s : s_sm[k];
    s_start_sh = s;
  }
  __syncthreads();
  const int s_start = s_start_sh;

  // init LDS bf16 state (h_init when starting at t=0, else zeros)
  for (int i = tid; i < MB_ * LS_; i += 512) {
    int m = i >> 8, k = i & (LS_ - 1);
    float v0 = 0.f, v1 = 0.f;
    if (s_start == 0) {
      v0 = h_init[(size_t)(b0 + m) * HID_ + k];
      v1 = h_init[(size_t)(b0 + m) * HID_ + LS_ + k];
    }
    h0b[m][k] = f2bf(v0);
    h1b[m][k] = f2bf(v1);
  }
  // fp32 register-resident state copy: lane owns rows m=mt*16+quad*4+r, col c0+lt*16+l15.
  float h0v[2][2][4], h1v[2][2][4];
#pragma unroll
  for (int lt = 0; lt < 2; ++lt)
#pragma unroll
    for (int mt = 0; mt < 2; ++mt)
#pragma unroll
      for (int r = 0; r < 4; ++r) {
        const int m = mt * 16 + quad * 4 + r;
        const int c = c0 + lt * 16 + l15;
        float v0 = 0.f, v1 = 0.f;
        if (s_start == 0) {
          v0 = h_init[(size_t)(b0 + m) * HID_ + c];
          v1 = h_init[(size_t)(b0 + m) * HID_ + LS_ + c];
        }
        h0v[lt][mt][r] = v0;
        h1v[lt][mt][r] = v1;
      }
  __syncthreads();

  const bf16x8v z8 = {0, 0, 0, 0, 0, 0, 0, 0};

  for (int t = s_start; t < t0 + TB_; ++t) {
    const bool wr = (t >= t0);   // block-uniform
    const int ridx = t * B_ + b0;
    const bool rs_a0 = RVAL(ridx + l15);
    const bool rs_a1 = RVAL(ridx + 16 + l15);
    bool rs_e[2][4];
#pragma unroll
    for (int mt = 0; mt < 2; ++mt)
#pragma unroll
      for (int r = 0; r < 4; ++r) rs_e[mt][r] = RVAL(ridx + mt * 16 + quad * 4 + r);

    // ================= layer 0 =================
    f32x4 a_r[2][2], a_z[2][2], a_i[2][2], a_h[2][2];  // [ls_tile][m_tile]
#pragma unroll
    for (int lt = 0; lt < 2; ++lt)
#pragma unroll
      for (int mt = 0; mt < 2; ++mt) {
        a_r[lt][mt] = (f32x4){0.f, 0.f, 0.f, 0.f};
        a_z[lt][mt] = (f32x4){0.f, 0.f, 0.f, 0.f};
        a_i[lt][mt] = (f32x4){0.f, 0.f, 0.f, 0.f};
        a_h[lt][mt] = (f32x4){0.f, 0.f, 0.f, 0.f};
      }

    // ig0 = obs @ W_c^T (NOT masked); obs is stream-once -> nontemporal loads
#pragma unroll
    for (int kc = 0; kc < 2; ++kc) {
      const float* p0 = obs + ((size_t)t * B_ + b0 + l15) * IN_ + kc * 32 + quad * 8;
      const float* p1 = p0 + (size_t)16 * IN_;
      f32x4 x0 = __builtin_nontemporal_load((const f32x4*)p0);
      f32x4 x1 = __builtin_nontemporal_load((const f32x4*)(p0 + 4));
      f32x4 y0 = __builtin_nontemporal_load((const f32x4*)p1);
      f32x4 y1 = __builtin_nontemporal_load((const f32x4*)(p1 + 4));
      bf16x8v a0, a1;
      a0[0] = (short)f2bf(x0[0]); a0[1] = (short)f2bf(x0[1]);
      a0[2] = (short)f2bf(x0[2]); a0[3] = (short)f2bf(x0[3]);
      a0[4] = (short)f2bf(x1[0]); a0[5] = (short)f2bf(x1[1]);
      a0[6] = (short)f2bf(x1[2]); a0[7] = (short)f2bf(x1[3]);
      a1[0] = (short)f2bf(y0[0]); a1[1] = (short)f2bf(y0[1]);
      a1[2] = (short)f2bf(y0[2]); a1[3] = (short)f2bf(y0[3]);
      a1[4] = (short)f2bf(y1[0]); a1[5] = (short)f2bf(y1[1]);
      a1[6] = (short)f2bf(y1[2]); a1[7] = (short)f2bf(y1[3]);
#pragma unroll
      for (int lt = 0; lt < 2; ++lt) {
        const int row = c0 + lt * 16 + l15;
        const unsigned short* pb = wc + (size_t)row * IN_ + kc * 32 + quad * 8;
        bf16x8v br = *(const bf16x8v*)pb;
        bf16x8v bz = *(const bf16x8v*)(pb + 256 * IN_);
        bf16x8v bn = *(const bf16x8v*)(pb + 512 * IN_);
        a_r[lt][0] = MFMA_B16(a0, br, a_r[lt][0]); a_r[lt][1] = MFMA_B16(a1, br, a_r[lt][1]);
        a_z[lt][0] = MFMA_B16(a0, bz, a_z[lt][0]); a_z[lt][1] = MFMA_B16(a1, bz, a_z[lt][1]);
        a_i[lt][0] = MFMA_B16(a0, bn, a_i[lt][0]); a_i[lt][1] = MFMA_B16(a1, bn, a_i[lt][1]);
      }
    }
    // h-side gates: (mask*h0) @ w_hh0^T
#pragma unroll
    for (int kc = 0; kc < 8; ++kc) {
      bf16x8v a0 = *(const bf16x8v*)&h0b[l15][kc * 32 + quad * 8];
      bf16x8v a1 = *(const bf16x8v*)&h0b[16 + l15][kc * 32 + quad * 8];
      if (rs_a0) a0 = z8;
      if (rs_a1) a1 = z8;
#pragma unroll
      for (int lt = 0; lt < 2; ++lt) {
        const int row = c0 + lt * 16 + l15;
        const unsigned short* pb = whh0 + (size_t)row * LS_ + kc * 32 + quad * 8;
        bf16x8v br = *(const bf16x8v*)pb;
        bf16x8v bz = *(const bf16x8v*)(pb + 256 * LS_);
        bf16x8v bn = *(const bf16x8v*)(pb + 512 * LS_);
        a_r[lt][0] = MFMA_B16(a0, br, a_r[lt][0]); a_r[lt][1] = MFMA_B16(a1, br, a_r[lt][1]);
        a_z[lt][0] = MFMA_B16(a0, bz, a_z[lt][0]); a_z[lt][1] = MFMA_B16(a1, bz, a_z[lt][1]);
        a_h[lt][0] = MFMA_B16(a0, bn, a_h[lt][0]); a_h[lt][1] = MFMA_B16(a1, bn, a_h[lt][1]);
      }
    }
    __syncthreads();  // S1: all h0 A-frag reads done before in-place h0n writes

    // epilogue 0: GRU cell, fp32 carry, write h0n (LDS bf16 + fp32 stage)
#pragma unroll
    for (int lt = 0; lt < 2; ++lt) {
      const int c = c0 + lt * 16 + l15;
      const float br_ = sbias[c] + sbias[G3_ + c];
      const float bz_ = sbias[c + 256] + sbias[G3_ + c + 256];
      const float bi_ = sbias[c + 512];
      const float bh_ = sbias[G3_ + c + 512];
#pragma unroll
      for (int mt = 0; mt < 2; ++mt)
#pragma unroll
        for (int r = 0; r < 4; ++r) {
          const int m = mt * 16 + quad * 4 + r;
          float rr = sigm(a_r[lt][mt][r] + br_);
          float zz = sigm(a_z[lt][mt][r] + bz_);
          float nn = tanh_f(a_i[lt][mt][r] + bi_ + rr * (a_h[lt][mt][r] + bh_));
          float hp = rs_e[mt][r] ? 0.f : h0v[lt][mt][r];
          float hv = (1.f - zz) * nn + zz * hp;
          h0v[lt][mt][r] = hv;
          h0b[m][c] = f2bf(hv);
          if (wr) ostage[m][c] = hv;
        }
    }
    __syncthreads();  // S2: h0n + stage complete before layer-1 reads / coop store

    // cooperative full-line NT store of layer-0 rows (1 KB contiguous per m-row)
    if (wr) {
#pragma unroll
      for (int it = 0; it < 4; ++it) {
        int i = tid + it * 512;          // 2048 float4 tiles: m = i>>6, c4 = i&63
        int m = i >> 6, c4 = i & 63;
        f32x4 v = *(const f32x4*)&ostage[m][c4 * 4];
        __builtin_nontemporal_store(v, (f32x4*)&out[((size_t)t * B_ + b0 + m) * HID_ + c4 * 4]);
      }
    }

    // ================= layer 1 =================
#pragma unroll
    for (int lt = 0; lt < 2; ++lt)
#pragma unroll
      for (int mt = 0; mt < 2; ++mt) {
        a_r[lt][mt] = (f32x4){0.f, 0.f, 0.f, 0.f};
        a_z[lt][mt] = (f32x4){0.f, 0.f, 0.f, 0.f};
        a_i[lt][mt] = (f32x4){0.f, 0.f, 0.f, 0.f};
        a_h[lt][mt] = (f32x4){0.f, 0.f, 0.f, 0.f};
      }
#pragma unroll
    for (int kc = 0; kc < 8; ++kc) {
      bf16x8v an0 = *(const bf16x8v*)&h0b[l15][kc * 32 + quad * 8];       // h0n (unmasked)
      bf16x8v an1 = *(const bf16x8v*)&h0b[16 + l15][kc * 32 + quad * 8];
      bf16x8v ah0 = *(const bf16x8v*)&h1b[l15][kc * 32 + quad * 8];       // mask*h1
      bf16x8v ah1 = *(const bf16x8v*)&h1b[16 + l15][kc * 32 + quad * 8];
      if (rs_a0) ah0 = z8;
      if (rs_a1) ah1 = z8;
#pragma unroll
      for (int lt = 0; lt < 2; ++lt) {
        const int row = c0 + lt * 16 + l15;
        const unsigned short* pi = wih1 + (size_t)row * LS_ + kc * 32 + quad * 8;
        const unsigned short* ph = whh1 + (size_t)row * LS_ + kc * 32 + quad * 8;
        bf16x8v bir = *(const bf16x8v*)pi;
        bf16x8v biz = *(const bf16x8v*)(pi + 256 * LS_);
        bf16x8v bin = *(const bf16x8v*)(pi + 512 * LS_);
        bf16x8v bhr = *(const bf16x8v*)ph;
        bf16x8v bhz = *(const bf16x8v*)(ph + 256 * LS_);
        bf16x8v bhn = *(const bf16x8v*)(ph + 512 * LS_);
        a_r[lt][0] = MFMA_B16(an0, bir, a_r[lt][0]);
        a_r[lt][0] = MFMA_B16(ah0, bhr, a_r[lt][0]);
        a_r[lt][1] = MFMA_B16(an1, bir, a_r[lt][1]);
        a_r[lt][1] = MFMA_B16(ah1, bhr, a_r[lt][1]);
        a_z[lt][0] = MFMA_B16(an0, biz, a_z[lt][0]);
        a_z[lt][0] = MFMA_B16(ah0, bhz, a_z[lt][0]);
        a_z[lt][1] = MFMA_B16(an1, biz, a_z[lt][1]);
        a_z[lt][1] = MFMA_B16(ah1, bhz, a_z[lt][1]);
        a_i[lt][0] = MFMA_B16(an0, bin, a_i[lt][0]);
        a_i[lt][1] = MFMA_B16(an1, bin, a_i[lt][1]);
        a_h[lt][0] = MFMA_B16(ah0, bhn, a_h[lt][0]);
        a_h[lt][1] = MFMA_B16(ah1, bhn, a_h[lt][1]);
      }
    }
    __syncthreads();  // S3: all h1 A-frag reads (and stage reads) done before writes

#pragma unroll
    for (int lt = 0; lt < 2; ++lt) {
      const int c = c0 + lt * 16 + l15;
      const float br_ = sbias[2 * G3_ + c] + sbias[3 * G3_ + c];
      const float bz_ = sbias[2 * G3_ + c + 256] + sbias[3 * G3_ + c + 256];
      const float bi_ = sbias[2 * G3_ + c + 512];
      const float bh_ = sbias[3 * G3_ + c + 512];
#pragma unroll
      for (int mt = 0; mt < 2; ++mt)
#pragma unroll
        for (int r = 0; r < 4; ++r) {
          const int m = mt * 16 + quad * 4 + r;
          float rr = sigm(a_r[lt][mt][r] + br_);
          float zz = sigm(a_z[lt][mt][r] + bz_);
          float nn = tanh_f(a_i[lt][mt][r] + bi_ + rr * (a_h[lt][mt][r] + bh_));
          float hp = rs_e[mt][r] ? 0.f : h1v[lt][mt][r];
          float hv = (1.f - zz) * nn + zz * hp;
          h1v[lt][mt][r] = hv;
          h1b[m][c] = f2bf(hv);
          if (wr) ostage[m][c] = hv;
        }
    }
    __syncthreads();  // S4: h1n + stage complete before coop store / next-iter reads

    if (wr) {
#pragma unroll
      for (int it = 0; it < 4; ++it) {
        int i = tid + it * 512;
        int m = i >> 6, c4 = i & 63;
        f32x4 v = *(const f32x4*)&ostage[m][c4 * 4];
        __builtin_nontemporal_store(v,
            (f32x4*)&out[((size_t)t * B_ + b0 + m) * HID_ + LS_ + c4 * 4]);
      }
    }
    // next-iter S1 orders these stores'/reads' LDS deps (stage rewritten after S1)
  }
#undef RVAL
}

extern "C" void kernel_launch(void* const* d_in, const int* in_sizes, int n_in,
                              void* d_out, int out_size, void* d_ws, size_t ws_size,
                              hipStream_t stream) {
  const float* obs    = (const float*)d_in[0];
  const unsigned char* rst = (const unsigned char*)d_in[1];
  const float* h_init = (const float*)d_in[2];
  const float* W_lin  = (const float*)d_in[3];
  const float* b_lin  = (const float*)d_in[4];
  const float* w_ih0  = (const float*)d_in[5];
  const float* w_hh0  = (const float*)d_in[6];
  const float* b_ih0  = (const float*)d_in[7];
  const float* b_hh0  = (const float*)d_in[8];
  const float* w_ih1  = (const float*)d_in[9];
  const float* w_hh1  = (const float*)d_in[10];
  const float* b_ih1  = (const float*)d_in[11];
  const float* b_hh1  = (const float*)d_in[12];

  // workspace carve (all 16B-aligned offsets); re-written every launch
  char* w = (char*)d_ws;
  unsigned short* wc    = (unsigned short*)(w);             // 768*64  bf16 =  98304 B
  unsigned short* whh0b = (unsigned short*)(w + 98304);     // 768*256 bf16 = 393216 B
  unsigned short* wih1b = (unsigned short*)(w + 491520);
  unsigned short* whh1b = (unsigned short*)(w + 884736);
  float*          bcp   = (float*)(w + 1277952);            // 768 f32
  int*            flagp = (int*)(w + 1281024);

  prep_conv<<<1152, 512, 0, stream>>>(w_hh0, w_ih1, w_hh1, rst, whh0b, flagp);
  prep_wc<<<768, 64, 0, stream>>>(W_lin, b_lin, w_ih0, b_ih0, wc, bcp);
  gru_main<<<dim3(NTB_, NBG_), 512, 0, stream>>>(obs, rst, h_init, wc, whh0b, wih1b, whh1b,
                                                 bcp, b_hh0, b_ih1, b_hh1, flagp,
                                                 (float*)d_out);
}

// Round 4
// 1198.423 us; speedup vs baseline: 1.0253x; 1.0033x over previous
//
#include <hip/hip_runtime.h>

// RecurrentModel: 2-layer GRU stack. Persistent-weight team design.
// 32 teams x 8 blocks. Team = (batch-group of 64) x (time-chunk of 32).
// Block j of a team owns hidden cols [32j,32j+32) of BOTH layers; its weight
// row-slices live in LDS for the whole kernel. Per step, teams exchange
// h-state slices via L2-resident d_ws buffers + device-scope atomic flags.
#define T_    256
#define B_    256
#define IN_   64
#define HID_  512
#define LS_   256
#define G3_   768
#define TBS_  32     // timesteps per team
#define MBT_  64     // batch rows per team
#define WP_   264    // LDS weight row pitch in shorts (528B: 16B-aligned, 2-way-bank free)

typedef short bf16x8v __attribute__((ext_vector_type(8)));
typedef float f32x4  __attribute__((ext_vector_type(4)));

#define MFMA_B16(A, B, C) __builtin_amdgcn_mfma_f32_16x16x32_bf16(A, B, C, 0, 0, 0)

__device__ __forceinline__ unsigned short f2bf(float f) {
  union { float f; unsigned u; } v; v.f = f;
  unsigned r = v.u + 0x7fffu + ((v.u >> 16) & 1u);   // RNE
  return (unsigned short)(r >> 16);
}
__device__ __forceinline__ float sigm(float x) { return 1.0f / (1.0f + __expf(-x)); }
__device__ __forceinline__ float tanh_f(float x) {
  x = fminf(fmaxf(x, -15.0f), 15.0f);
  float e = __expf(-2.0f * x);
  return (1.0f - e) / (1.0f + e);
}

// ---------------- prep 1: bf16 weight conversion + reset sniff + flag zero ----
__global__ void prep_conv(const float* __restrict__ whh0, const float* __restrict__ wih1,
                          const float* __restrict__ whh1, const unsigned char* __restrict__ rst,
                          unsigned short* __restrict__ dst, int* __restrict__ flagp,
                          int* __restrict__ flags) {
  const int idx = blockIdx.x * blockDim.x + threadIdx.x;
  const int N1 = G3_ * LS_;
  if (idx < 3 * N1) {
    float v;
    if (idx < N1)            v = whh0[idx];
    else if (idx < 2 * N1)   v = wih1[idx - N1];
    else                     v = whh1[idx - 2 * N1];
    dst[idx] = f2bf(v);
  }
  if (blockIdx.x == 1 && threadIdx.x < 64) flags[threadIdx.x] = 0;  // flag0[32]|flag1[32]
  if (blockIdx.x == 0) {
    __shared__ int f;
    if (threadIdx.x == 0) f = 0;
    __syncthreads();
    int any = 0;
    for (int i = 0; i < 8; ++i) {
      int off = threadIdx.x * 8 + i;
      if ((off & 3) && rst[off]) any = 1;
    }
    if (any) atomicOr(&f, 1);
    __syncthreads();
    if (threadIdx.x == 0) *flagp = f;   // 1 => byte-packed reset
  }
}

// ---------------- prep 2: fused embed W_c = w_ih0 @ W_lin, b_c --------------
__global__ void prep_wc(const float* __restrict__ W_lin, const float* __restrict__ b_lin,
                        const float* __restrict__ w_ih0, const float* __restrict__ b_ih0,
                        unsigned short* __restrict__ wc, float* __restrict__ bc) {
  const int n = blockIdx.x;
  const int i = threadIdx.x;
  const float* wrow = w_ih0 + (size_t)n * HID_;
  float acc = 0.f;
  for (int h = 0; h < HID_; ++h) acc += wrow[h] * W_lin[h * IN_ + i];
  wc[n * IN_ + i] = f2bf(acc);
  float pb = 0.f;
  for (int h = i; h < HID_; h += 64) pb += wrow[h] * b_lin[h];
  __shared__ float red[64];
  red[i] = pb;
  __syncthreads();
  if (i == 0) {
    float s = 0.f;
    for (int k = 0; k < 64; ++k) s += red[k];
    bc[n] = s + b_ih0[n];
  }
}

// ---------------- main: persistent-weight recurrent kernel ------------------
__global__ __launch_bounds__(512, 2) void gru_main(
    const float* __restrict__ obs, const unsigned char* __restrict__ rst,
    const float* __restrict__ h_init,
    const unsigned short* __restrict__ wc,     // [768][64] bf16 (global, L2-hot)
    const unsigned short* __restrict__ whh0g,  // [768][256] bf16
    const unsigned short* __restrict__ wih1g, const unsigned short* __restrict__ whh1g,
    const float* __restrict__ bcp, const float* __restrict__ bhh0,
    const float* __restrict__ bih1, const float* __restrict__ bhh1,
    const int* __restrict__ flagp, int* __restrict__ flag0, int* __restrict__ flag1,
    unsigned short* __restrict__ hx0, unsigned short* __restrict__ hx1,
    float* __restrict__ out) {

  // Weight slices, persistent all-kernel: [whh0 | wih1 | whh1], 96 rows x 264 pitch
  __shared__ __align__(16) unsigned short wlds[3 * 96 * WP_];   // 152064 B
  __shared__ int s_sm[64];
  __shared__ int s_start_sh;

  const int tid  = threadIdx.x;
  const int lane = tid & 63;
  const int wave = tid >> 6;
  const int l15  = lane & 15;
  const int quad = lane >> 4;
  const int mt   = wave & 3;            // m16 tile (batch rows mt*16..+16)
  const int c16  = (wave >> 2) * 16;    // col-16 half of the 32-col slice

  // block -> (team, slice j); bx&7 ~ XCD heuristic (correctness-independent)
  const int x  = blockIdx.x;
  const int cx = x & 7, m8 = x >> 3;
  const int j  = m8 & 7;                // col-slice 0..7
  const int team = cx * 4 + (m8 >> 3);  // 0..31 (4 teams per XCD)
  const int bg = team & 3, tc = team >> 2;
  const int b0 = bg * MBT_, t0 = tc * TBS_;

  const int flag = *flagp;
#define RVAL(i) (rst[flag ? (i) : ((i) << 2)] != 0)

  // ---- stage weight slices into LDS (once) ----
#pragma unroll
  for (int q = 0; q < 3; ++q) {
    const unsigned short* src = (q == 0) ? whh0g : (q == 1) ? wih1g : whh1g;
    for (int cid = tid; cid < 96 * 32; cid += 512) {      // 16B chunks
      int lr = cid >> 5, off8 = (cid & 31) * 8;           // row, short-offset
      int g = lr >> 5, cc = lr & 31;
      int grow = (g << 8) + (j << 5) + cc;                // g*256 + j*32 + cc
      *(f32x4*)&wlds[(q * 96 + lr) * WP_ + off8] =
          *(const f32x4*)&src[(size_t)grow * 256 + off8];
    }
  }

  // ---- per-lane biases (cols this wave computes) ----
  const int colg = j * 32 + c16 + l15;   // 0..255 within layer
  const float b0r = bcp[colg] + bhh0[colg];
  const float b0z = bcp[256 + colg] + bhh0[256 + colg];
  const float b0i = bcp[512 + colg];
  const float b0h = bhh0[512 + colg];
  const float b1r = bih1[colg] + bhh1[colg];
  const float b1z = bih1[256 + colg] + bhh1[256 + colg];
  const float b1i = bih1[512 + colg];
  const float b1h = bhh1[512 + colg];

  // ---- team-uniform safe start (last reset <= t0 across the 64 batch rows) ----
  if (tid < 64) {
    int s = 0;
    for (int tt = t0; tt >= 1; --tt) {
      if (RVAL(tt * B_ + b0 + tid)) { s = tt; break; }
    }
    s_sm[tid] = s;
  }
  __syncthreads();
  if (tid == 0) {
    int s = s_sm[0];
    for (int k = 1; k < 64; ++k) s = s < s_sm[k] ? s : s_sm[k];
    s_start_sh = s;
  }
  __syncthreads();
  const int s_start = s_start_sh;   // identical across the 8 sibling blocks

  // ---- init A-fragments (full h rows mt*16+l15) and fp32 carries ----
  bf16x8v h0A[8], h1A[8];
  const bf16x8v z8 = {0, 0, 0, 0, 0, 0, 0, 0};
#pragma unroll
  for (int kc = 0; kc < 8; ++kc) { h0A[kc] = z8; h1A[kc] = z8; }
  float h0v[4] = {0.f, 0.f, 0.f, 0.f}, h1v[4] = {0.f, 0.f, 0.f, 0.f};
  if (s_start == 0) {
    const float* hrow = h_init + (size_t)(b0 + mt * 16 + l15) * HID_;
#pragma unroll
    for (int kc = 0; kc < 8; ++kc) {
      f32x4 u0 = *(const f32x4*)(hrow + kc * 32 + quad * 8);
      f32x4 u1 = *(const f32x4*)(hrow + kc * 32 + quad * 8 + 4);
      f32x4 v0 = *(const f32x4*)(hrow + 256 + kc * 32 + quad * 8);
      f32x4 v1 = *(const f32x4*)(hrow + 256 + kc * 32 + quad * 8 + 4);
      bf16x8v a, b;
#pragma unroll
      for (int e = 0; e < 4; ++e) {
        a[e] = (short)f2bf(u0[e]); a[4 + e] = (short)f2bf(u1[e]);
        b[e] = (short)f2bf(v0[e]); b[4 + e] = (short)f2bf(v1[e]);
      }
      h0A[kc] = a; h1A[kc] = b;
    }
#pragma unroll
    for (int r = 0; r < 4; ++r) {
      const int m = mt * 16 + quad * 4 + r;
      h0v[r] = h_init[(size_t)(b0 + m) * HID_ + colg];
      h1v[r] = h_init[(size_t)(b0 + m) * HID_ + 256 + colg];
    }
  }

  const unsigned short* wR0 = &wlds[(0 * 96 + 0 * 32 + c16 + l15) * WP_];
  const unsigned short* wZ0 = &wlds[(0 * 96 + 1 * 32 + c16 + l15) * WP_];
  const unsigned short* wN0 = &wlds[(0 * 96 + 2 * 32 + c16 + l15) * WP_];
  const unsigned short* iR1 = &wlds[(1 * 96 + 0 * 32 + c16 + l15) * WP_];
  const unsigned short* iZ1 = &wlds[(1 * 96 + 1 * 32 + c16 + l15) * WP_];
  const unsigned short* iN1 = &wlds[(1 * 96 + 2 * 32 + c16 + l15) * WP_];
  const unsigned short* hR1 = &wlds[(2 * 96 + 0 * 32 + c16 + l15) * WP_];
  const unsigned short* hZ1 = &wlds[(2 * 96 + 1 * 32 + c16 + l15) * WP_];
  const unsigned short* hN1 = &wlds[(2 * 96 + 2 * 32 + c16 + l15) * WP_];

  for (int t = s_start; t < t0 + TBS_; ++t) {
    const int  kk = t - s_start + 1;          // 1-based team step counter
    const bool wr = (t >= t0);
    const bool rs0 = RVAL(t * B_ + b0 + mt * 16 + l15);   // A-row mask
    bool rse[4];
#pragma unroll
    for (int r = 0; r < 4; ++r) rse[r] = RVAL(t * B_ + b0 + mt * 16 + quad * 4 + r);

    // ============ layer 0 ============
    f32x4 ar = {0.f, 0.f, 0.f, 0.f}, az = ar, ani = ar, anh = ar;
    // input side: obs @ W_c^T (K=64)
    {
      const float* po = obs + ((size_t)t * B_ + b0 + mt * 16 + l15) * IN_;
#pragma unroll
      for (int kc = 0; kc < 2; ++kc) {
        f32x4 u0 = __builtin_nontemporal_load((const f32x4*)(po + kc * 32 + quad * 8));
        f32x4 u1 = __builtin_nontemporal_load((const f32x4*)(po + kc * 32 + quad * 8 + 4));
        bf16x8v oA;
#pragma unroll
        for (int e = 0; e < 4; ++e) { oA[e] = (short)f2bf(u0[e]); oA[4 + e] = (short)f2bf(u1[e]); }
        const size_t wo = (size_t)colg * 64 + kc * 32 + quad * 8;
        bf16x8v br = *(const bf16x8v*)&wc[wo];
        bf16x8v bz = *(const bf16x8v*)&wc[wo + (size_t)256 * 64];
        bf16x8v bn = *(const bf16x8v*)&wc[wo + (size_t)512 * 64];
        ar  = MFMA_B16(oA, br, ar);
        az  = MFMA_B16(oA, bz, az);
        ani = MFMA_B16(oA, bn, ani);
      }
    }
    // h side: (mask*h0[t-1]) @ whh0^T (K=256, LDS weights)
#pragma unroll
    for (int kc = 0; kc < 8; ++kc) {
      bf16x8v am = rs0 ? z8 : h0A[kc];
      const int o = kc * 32 + quad * 8;
      ar  = MFMA_B16(am, *(const bf16x8v*)&wR0[o], ar);
      az  = MFMA_B16(am, *(const bf16x8v*)&wZ0[o], az);
      anh = MFMA_B16(am, *(const bf16x8v*)&wN0[o], anh);
    }
    // epilogue 0: fp32 carry, publish slice, out
    {
      unsigned short* hw = hx0 + ((size_t)team * 2 + (kk & 1)) * (MBT_ * 256);
#pragma unroll
      for (int r = 0; r < 4; ++r) {
        const int m = mt * 16 + quad * 4 + r;
        float rr = sigm(ar[r] + b0r);
        float zz = sigm(az[r] + b0z);
        float nn = tanh_f(ani[r] + b0i + rr * (anh[r] + b0h));
        float hp = rse[r] ? 0.f : h0v[r];
        float hv = (1.f - zz) * nn + zz * hp;
        h0v[r] = hv;
        hw[m * 256 + colg] = f2bf(hv);
        if (wr) __builtin_nontemporal_store(hv, &out[((size_t)t * B_ + b0 + m) * HID_ + colg]);
      }
    }
    // ---- rendezvous: publish h0 slice; wait team h0[kk] and h1[kk-1] ----
    __syncthreads();   // drains vmem (compiler emits vmcnt(0) before barrier)
    if (tid == 0) {
      __hip_atomic_fetch_add(flag0 + team, 1, __ATOMIC_RELEASE, __HIP_MEMORY_SCOPE_AGENT);
      int cap = 0;
      while (__hip_atomic_load(flag0 + team, __ATOMIC_ACQUIRE, __HIP_MEMORY_SCOPE_AGENT)
                 < 8 * kk && cap < (1 << 16)) { __builtin_amdgcn_s_sleep(32); ++cap; }
      if (kk >= 2) {
        cap = 0;
        while (__hip_atomic_load(flag1 + team, __ATOMIC_ACQUIRE, __HIP_MEMORY_SCOPE_AGENT)
                   < 8 * (kk - 1) && cap < (1 << 16)) { __builtin_amdgcn_s_sleep(32); ++cap; }
      }
    }
    __syncthreads();
    // refresh full-row A-frags: h0n[t] (fresh) and h1n[t-1]
    {
      const unsigned short* hr0 =
          hx0 + ((size_t)team * 2 + (kk & 1)) * (MBT_ * 256) + (mt * 16 + l15) * 256;
#pragma unroll
      for (int kc = 0; kc < 8; ++kc)
        h0A[kc] = *(const bf16x8v*)&hr0[kc * 32 + quad * 8];
      if (kk >= 2) {
        const unsigned short* hr1 =
            hx1 + ((size_t)team * 2 + ((kk - 1) & 1)) * (MBT_ * 256) + (mt * 16 + l15) * 256;
#pragma unroll
        for (int kc = 0; kc < 8; ++kc)
          h1A[kc] = *(const bf16x8v*)&hr1[kc * 32 + quad * 8];
      }
    }

    // ============ layer 1 ============
    ar = (f32x4){0.f, 0.f, 0.f, 0.f}; az = ar; ani = ar; anh = ar;
#pragma unroll
    for (int kc = 0; kc < 8; ++kc) {
      bf16x8v ai_ = h0A[kc];                 // h0n[t], unmasked
      bf16x8v am  = rs0 ? z8 : h1A[kc];      // mask*h1[t-1]
      const int o = kc * 32 + quad * 8;
      ar  = MFMA_B16(ai_, *(const bf16x8v*)&iR1[o], ar);
      az  = MFMA_B16(ai_, *(const bf16x8v*)&iZ1[o], az);
      ani = MFMA_B16(ai_, *(const bf16x8v*)&iN1[o], ani);
      ar  = MFMA_B16(am, *(const bf16x8v*)&hR1[o], ar);
      az  = MFMA_B16(am, *(const bf16x8v*)&hZ1[o], az);
      anh = MFMA_B16(am, *(const bf16x8v*)&hN1[o], anh);
    }
    // epilogue 1
    {
      unsigned short* hw = hx1 + ((size_t)team * 2 + (kk & 1)) * (MBT_ * 256);
#pragma unroll
      for (int r = 0; r < 4; ++r) {
        const int m = mt * 16 + quad * 4 + r;
        float rr = sigm(ar[r] + b1r);
        float zz = sigm(az[r] + b1z);
        float nn = tanh_f(ani[r] + b1i + rr * (anh[r] + b1h));
        float hp = rse[r] ? 0.f : h1v[r];
        float hv = (1.f - zz) * nn + zz * hp;
        h1v[r] = hv;
        hw[m * 256 + colg] = f2bf(hv);
        if (wr) __builtin_nontemporal_store(hv, &out[((size_t)t * B_ + b0 + m) * HID_ + 256 + colg]);
      }
    }
    __syncthreads();
    if (tid == 0)
      __hip_atomic_fetch_add(flag1 + team, 1, __ATOMIC_RELEASE, __HIP_MEMORY_SCOPE_AGENT);
    // (h1[kk] readers wait at next step's rendezvous; buffer-overwrite safety
    //  follows from flag0>=8kk implying all siblings finished step kk-1 reads)
  }
#undef RVAL
}

extern "C" void kernel_launch(void* const* d_in, const int* in_sizes, int n_in,
                              void* d_out, int out_size, void* d_ws, size_t ws_size,
                              hipStream_t stream) {
  const float* obs    = (const float*)d_in[0];
  const unsigned char* rst = (const unsigned char*)d_in[1];
  const float* h_init = (const float*)d_in[2];
  const float* W_lin  = (const float*)d_in[3];
  const float* b_lin  = (const float*)d_in[4];
  const float* w_ih0  = (const float*)d_in[5];
  const float* w_hh0  = (const float*)d_in[6];
  const float* b_ih0  = (const float*)d_in[7];
  const float* b_hh0  = (const float*)d_in[8];
  const float* w_ih1  = (const float*)d_in[9];
  const float* w_hh1  = (const float*)d_in[10];
  const float* b_ih1  = (const float*)d_in[11];
  const float* b_hh1  = (const float*)d_in[12];

  // workspace carve (re-initialized every launch; ws is re-poisoned by harness)
  char* w = (char*)d_ws;
  unsigned short* wcp   = (unsigned short*)(w);              // 98304 B
  unsigned short* whh0b = (unsigned short*)(w + 98304);      // 393216 B
  unsigned short* wih1b = (unsigned short*)(w + 491520);
  unsigned short* whh1b = (unsigned short*)(w + 884736);
  float*          bcp   = (float*)(w + 1277952);             // 3072 B
  int*            flagp = (int*)(w + 1281024);               // 16 B
  int*            flags = (int*)(w + 1281088);               // 64 ints: flag0|flag1
  unsigned short* hx0   = (unsigned short*)(w + 1310720);    // 32*2*64*256*2 = 2 MiB
  unsigned short* hx1   = (unsigned short*)(w + 1310720 + 2097152);

  prep_conv<<<1152, 512, 0, stream>>>(w_hh0, w_ih1, w_hh1, rst, whh0b, flagp, flags);
  prep_wc<<<768, 64, 0, stream>>>(W_lin, b_lin, w_ih0, b_ih0, wcp, bcp);
  gru_main<<<256, 512, 0, stream>>>(obs, rst, h_init, wcp, whh0b, wih1b, whh1b,
                                    bcp, b_hh0, b_ih1, b_hh1, flagp,
                                    flags, flags + 32, hx0, hx1, (float*)d_out);
}